// Round 11
// baseline (1174.228 us; speedup 1.0000x reference)
//
#include <hip/hip_runtime.h>
#include <math.h>

#define DIM 64
#define EPSF 1e-15f

#define BW_SHIFT 7
#define BW (1 << BW_SHIFT)       // nodes per bucket (128)
#define CAP_SHIFT 11
#define CAP (1 << CAP_SHIFT)     // bucket capacity 2048 (mean ~1535, ~13 sigma)
#define NBMAX 1024
#define ASTRIDE 68               // accum row stride in floats (16B-aligned, bank-spread)
// NOTE: packing assumes src < 2^17 (N <= 131072) and NB <= 1024.

typedef __attribute__((ext_vector_type(8))) short short8;
typedef __attribute__((ext_vector_type(4))) float floatx4;
typedef __attribute__((ext_vector_type(4))) unsigned int uintx4;

// ---------------------------------------------------------------------------
__device__ __forceinline__ float group16_sum(float x) {
#pragma unroll
    for (int off = 1; off <= 8; off <<= 1)
        x += __shfl_xor(x, off, 64);
    return x;
}
__device__ __forceinline__ float group8_sum(float x) {
#pragma unroll
    for (int off = 1; off <= 4; off <<= 1)
        x += __shfl_xor(x, off, 64);
    return x;
}
__device__ __forceinline__ unsigned int f2bf(float x) {
    unsigned int u = __float_as_uint(x);
    u += 0x7fffu + ((u >> 16) & 1u);
    return u >> 16;
}
__device__ __forceinline__ float bflo(unsigned int u) { return __uint_as_float(u << 16); }
__device__ __forceinline__ float bfhi(unsigned int u) { return __uint_as_float(u & 0xFFFF0000u); }

// ---------------------------------------------------------------------------
// One-time prep: W->bf16, zero-row, bucket cursors to fixed bases b*CAP.
__global__ void prep_kernel(const float* __restrict__ W1, const float* __restrict__ W2,
                            unsigned short* __restrict__ Wbf1, unsigned short* __restrict__ Wbf2,
                            unsigned short* __restrict__ zrowb, int* __restrict__ cursorB) {
    int i = blockIdx.x * 256 + threadIdx.x;
    if (i < DIM * DIM) {
        Wbf1[i] = (unsigned short)f2bf(W1[i]);
        Wbf2[i] = (unsigned short)f2bf(W2[i]);
    }
    if (i < NBMAX) cursorB[i] = i << CAP_SHIFT;
    if (blockIdx.x == 0 && threadIdx.x < 64) zrowb[threadIdx.x] = 0;
}

// ---------------------------------------------------------------------------
// Merged dispatch: blocks [0, numChunks) partition edges into bucket regions
// of pairBuf (packed = (dst & (BW-1)) << 17 | src); remaining blocks run
// layer-1 logmap+GEMM (independent of the CSR build).
union SharedP {
    struct { int hist[NBMAX]; int gbase[NBMAX]; int lcur[NBMAX]; } p;  // 12 KB
    unsigned int atile[4][16 * 36];                                    // 9.2 KB
};

__global__ __launch_bounds__(256, 4) void partition_and_gemm_kernel(
    const int* __restrict__ src, const int* __restrict__ dst,
    int* __restrict__ cursorB, unsigned int* __restrict__ pairBuf,
    const float* __restrict__ in, const unsigned short* __restrict__ Wbf,
    const float* __restrict__ bias, const float* __restrict__ curv,
    unsigned short* __restrict__ outb, int N, int E, int NB, int numChunks)
{
    __shared__ SharedP u;
    if ((int)blockIdx.x < numChunks) {
        int tid = threadIdx.x;
        for (int t = tid; t < NB; t += 256) { u.p.hist[t] = 0; u.p.lcur[t] = 0; }
        __syncthreads();
        int base = blockIdx.x * 4096;
        unsigned int packed[16]; int bkt[16];
#pragma unroll
        for (int i = 0; i < 16; ++i) {
            int e = base + i * 256 + tid;
            if (e < E) {
                int s = src[e], d = dst[e];
                bkt[i] = d >> BW_SHIFT;
                packed[i] = ((unsigned int)(d & (BW - 1)) << 17) | (unsigned int)s;
                atomicAdd(&u.p.hist[bkt[i]], 1);
            } else bkt[i] = -1;
        }
        __syncthreads();
        for (int t = tid; t < NB; t += 256)
            u.p.gbase[t] = u.p.hist[t] ? atomicAdd(&cursorB[t], u.p.hist[t]) : 0;
        __syncthreads();
#pragma unroll
        for (int i = 0; i < 16; ++i) {
            if (bkt[i] >= 0) {
                int rank = atomicAdd(&u.p.lcur[bkt[i]], 1);
                int p = u.p.gbase[bkt[i]] + rank;
                if (p < ((bkt[i] + 1) << CAP_SHIFT)) pairBuf[p] = packed[i];  // overflow guard
            }
        }
    } else {
        // ---- layer 1: t = logmap0(in); h1 = t @ W^T + b -> bf16, MFMA ----
        const int bid = blockIdx.x - numChunks;
        const int gemmWaves = (gridDim.x - numChunks) << 2;
        const float sc = sqrtf(fabsf(curv[0]));
        const float CLIPF = 1.0f - 1e-7f;
        const int lane = threadIdx.x & 63;
        const int wid  = threadIdx.x >> 6;
        const int q = lane >> 4, r = lane & 15;
        const int numBatches = (N + 15) >> 4;
        const float4* in4 = (const float4*)in;

        short8 bfrag[4][2];
#pragma unroll
        for (int nt = 0; nt < 4; ++nt)
#pragma unroll
            for (int ks = 0; ks < 2; ++ks)
                bfrag[nt][ks] = *(const short8*)(Wbf + (nt * 16 + r) * 64 + ks * 32 + q * 8);

        float biasv[4];
#pragma unroll
        for (int nt = 0; nt < 4; ++nt) biasv[nt] = bias[nt * 16 + r];

        for (int batch = (bid << 2) + wid; batch < numBatches; batch += gemmWaves) {
            const int base = batch << 4;
#pragma unroll
            for (int it = 0; it < 4; ++it) {
                int m = it * 4 + q;
                int node = base + m;
                float4 v = make_float4(0.f, 0.f, 0.f, 0.f);
                if (node < N) v = in4[(size_t)node * 16 + r];
                float ss = group16_sum(v.x * v.x + v.y * v.y + v.z * v.z + v.w * v.w);
                float nrm = fmaxf(sqrtf(ss), EPSF);
                float a = fminf(sc * nrm, CLIPF);
                float g = atanhf(a) / (sc * nrm);
                unsigned int lo = f2bf(v.x * g) | (f2bf(v.y * g) << 16);
                unsigned int hi = f2bf(v.z * g) | (f2bf(v.w * g) << 16);
                *(uint2*)&u.atile[wid][m * 36 + r * 2] = make_uint2(lo, hi);
            }
            floatx4 accm[4];
#pragma unroll
            for (int nt = 0; nt < 4; ++nt) accm[nt] = (floatx4){0.f, 0.f, 0.f, 0.f};
#pragma unroll
            for (int ks = 0; ks < 2; ++ks) {
                uintx4 ua = *(const uintx4*)&u.atile[wid][r * 36 + q * 4 + ks * 16];
                short8 af = __builtin_bit_cast(short8, ua);
#pragma unroll
                for (int nt = 0; nt < 4; ++nt)
                    accm[nt] = __builtin_amdgcn_mfma_f32_16x16x32_bf16(af, bfrag[nt][ks], accm[nt], 0, 0, 0);
            }
#pragma unroll
            for (int nt = 0; nt < 4; ++nt)
#pragma unroll
                for (int reg = 0; reg < 4; ++reg) {
                    int node = base + q * 4 + reg;
                    if (node < N)
                        outb[(size_t)node * 64 + nt * 16 + r] =
                            (unsigned short)f2bf(accm[nt][reg] + biasv[nt]);
                }
        }
    }
}

// ---------------------------------------------------------------------------
// Edge-centric LDS accumulate (shared by both gather kernels, duplicated
// inline to keep LDS address-space inference). See macro below.
// Per 8-edge group: 8 lanes load one 16B chunk of h[src] each (independent,
// high MLP) and ds_add_f32 into accum[dstLocal]. Rotated add order
// jj=(j+r8)&7 spreads banks. Invalid slots -> zrow load + trash row BW.
#define EDGE_ACCUMULATE(accumArr, degArr, hb_, pairBuf_, base_, cnt_, zoff_)      \
    {                                                                             \
        for (int i = (wid << 6); i < (cnt_); i += 256) {                          \
            int pos = i + lane;                                                   \
            unsigned int p = (pos < (cnt_)) ? (pairBuf_)[(base_) + pos]           \
                                            : 0xFFFFFFFFu;                        \
            _Pragma("unroll")                                                     \
            for (int sub = 0; sub < 8; ++sub) {                                   \
                unsigned int pe = __shfl(p, (sub << 3) + g8, 64);                 \
                bool bad = (pe == 0xFFFFFFFFu);                                   \
                long long off = bad ? (zoff_)                                     \
                                    : ((long long)(pe & 0x1FFFF) << 7);           \
                int d = bad ? BW : (int)(pe >> 17);                               \
                uint4 uu = *(const uint4*)((hb_) + off + (r8 << 4));              \
                float ff[8] = { bflo(uu.x), bfhi(uu.x), bflo(uu.y), bfhi(uu.y),   \
                                bflo(uu.z), bfhi(uu.z), bflo(uu.w), bfhi(uu.w) }; \
                float* arow = &(accumArr)[d * ASTRIDE + (r8 << 3)];               \
                _Pragma("unroll")                                                 \
                for (int j = 0; j < 8; ++j) {                                     \
                    int jj = (j + r8) & 7;                                        \
                    atomicAdd(&arow[jj], ff[jj]);                                 \
                }                                                                 \
                if (r8 == 0) atomicAdd(&(degArr)[d], 1.0f);                       \
            }                                                                     \
        }                                                                         \
    }

// ---------------------------------------------------------------------------
// Layer 2: block per bucket. Accumulate h1 rows into LDS, then
// u = accum/deg; h2 = u @ W2^T + b2 -> bf16 via MFMA straight from LDS.
__global__ __launch_bounds__(256, 4) void gather_acc_gemm(
    const unsigned short* __restrict__ h, const unsigned int* __restrict__ pairBuf,
    const int* __restrict__ cursorB, const unsigned short* __restrict__ Wbf,
    const float* __restrict__ bias, unsigned short* __restrict__ outb,
    long long zoff, int N)
{
    __shared__ float accum[(BW + 1) * ASTRIDE];   // 129x68 fp32 = 35.1 KB
    __shared__ float degL[BW + 4];
    const int tid = threadIdx.x;
    const int lane = tid & 63, wid = tid >> 6;
    const int q = lane >> 4, r = lane & 15;
    const int g8 = lane >> 3, r8 = lane & 7;
    const char* hb = (const char*)h;
    const int b = blockIdx.x;
    const int base = b << CAP_SHIFT;
    const int nodeBase = b << BW_SHIFT;

    for (int i = tid; i < (BW + 1) * ASTRIDE; i += 256) accum[i] = 0.f;
    if (tid < BW + 4) degL[tid] = 0.f;

    short8 bfrag[4][2];
#pragma unroll
    for (int nt = 0; nt < 4; ++nt)
#pragma unroll
        for (int ks = 0; ks < 2; ++ks)
            bfrag[nt][ks] = *(const short8*)(Wbf + (nt * 16 + r) * 64 + ks * 32 + q * 8);
    float biasv[4];
#pragma unroll
    for (int nt = 0; nt < 4; ++nt) biasv[nt] = bias[nt * 16 + r];

    int cnt = cursorB[b] - base;
    if (cnt > CAP) cnt = CAP;
    __syncthreads();

    EDGE_ACCUMULATE(accum, degL, hb, pairBuf, base, cnt, zoff);
    __syncthreads();

    // ---- mean + GEMM2 per 16-node batch (8 batches, 2 per wave) ----
#pragma unroll
    for (int bi = 0; bi < 2; ++bi) {
        int bt = wid * 2 + bi;
        float dg = degL[bt * 16 + r];
        float inv = (dg > 0.f) ? 1.f / dg : 0.f;
        floatx4 accm[4];
#pragma unroll
        for (int nt = 0; nt < 4; ++nt) accm[nt] = (floatx4){0.f, 0.f, 0.f, 0.f};
#pragma unroll
        for (int ks = 0; ks < 2; ++ks) {
            const float* ap = &accum[(bt * 16 + r) * ASTRIDE + ks * 32 + (q << 3)];
            float4 a0 = *(const float4*)ap;
            float4 a1 = *(const float4*)(ap + 4);
            unsigned int u0 = f2bf(a0.x * inv) | (f2bf(a0.y * inv) << 16);
            unsigned int u1 = f2bf(a0.z * inv) | (f2bf(a0.w * inv) << 16);
            unsigned int u2 = f2bf(a1.x * inv) | (f2bf(a1.y * inv) << 16);
            unsigned int u3 = f2bf(a1.z * inv) | (f2bf(a1.w * inv) << 16);
            uintx4 ua = {u0, u1, u2, u3};
            short8 af = __builtin_bit_cast(short8, ua);
#pragma unroll
            for (int nt = 0; nt < 4; ++nt)
                accm[nt] = __builtin_amdgcn_mfma_f32_16x16x32_bf16(af, bfrag[nt][ks], accm[nt], 0, 0, 0);
        }
#pragma unroll
        for (int nt = 0; nt < 4; ++nt)
#pragma unroll
            for (int reg = 0; reg < 4; ++reg) {
                int node = nodeBase + bt * 16 + q * 4 + reg;
                if (node < N)
                    outb[(size_t)node * 64 + nt * 16 + r] =
                        (unsigned short)f2bf(accm[nt][reg] + biasv[nt]);
            }
    }
}

// ---------------------------------------------------------------------------
// Final: block per bucket. Accumulate h2 rows, then out = expmap0(accum/deg).
__global__ __launch_bounds__(256, 4) void gather_acc_expmap(
    const unsigned short* __restrict__ h, const unsigned int* __restrict__ pairBuf,
    const int* __restrict__ cursorB, const float* __restrict__ curv,
    float* __restrict__ out, long long zoff, int N)
{
    __shared__ float accum[(BW + 1) * ASTRIDE];
    __shared__ float degL[BW + 4];
    const int tid = threadIdx.x;
    const int lane = tid & 63, wid = tid >> 6;
    const int g8 = lane >> 3, r8 = lane & 7;
    const char* hb = (const char*)h;
    const int b = blockIdx.x;
    const int base = b << CAP_SHIFT;
    const int nodeBase = b << BW_SHIFT;
    const float sc = sqrtf(fabsf(curv[0]));
    float4* out4 = (float4*)out;

    for (int i = tid; i < (BW + 1) * ASTRIDE; i += 256) accum[i] = 0.f;
    if (tid < BW + 4) degL[tid] = 0.f;
    int cnt = cursorB[b] - base;
    if (cnt > CAP) cnt = CAP;
    __syncthreads();

    EDGE_ACCUMULATE(accum, degL, hb, pairBuf, base, cnt, zoff);
    __syncthreads();

    // ---- mean + expmap0 (32 nodes per pass: 4 waves x 8 nodes) ----
#pragma unroll
    for (int pass = 0; pass < 4; ++pass) {
        int localn = pass * 32 + (wid << 3) + g8;
        int node = nodeBase + localn;
        float dg = degL[localn];
        float inv = (dg > 0.f) ? 1.f / dg : 0.f;
        const float* ap = &accum[localn * ASTRIDE + (r8 << 3)];
        float v[8], ss = 0.f;
#pragma unroll
        for (int j = 0; j < 8; ++j) { v[j] = ap[j] * inv; ss += v[j] * v[j]; }
        ss = group8_sum(ss);
        float nrm = fmaxf(sqrtf(ss), EPSF);
        float a = sc * nrm;
        float f = tanhf(a) / a;
        if (node < N) {
            out4[(size_t)node * 16 + r8 * 2]     = make_float4(v[0] * f, v[1] * f, v[2] * f, v[3] * f);
            out4[(size_t)node * 16 + r8 * 2 + 1] = make_float4(v[4] * f, v[5] * f, v[6] * f, v[7] * f);
        }
    }
}

// ---------------------------------------------------------------------------
extern "C" void kernel_launch(void* const* d_in, const int* in_sizes, int n_in,
                              void* d_out, int out_size, void* d_ws, size_t ws_size,
                              hipStream_t stream)
{
    const int*   src  = (const int*)d_in[0];
    const int*   dst  = (const int*)d_in[1];
    const float* emb  = (const float*)d_in[2];
    const float* W1   = (const float*)d_in[3];
    const float* b1   = (const float*)d_in[4];
    const float* W2   = (const float*)d_in[5];
    const float* b2   = (const float*)d_in[6];
    const float* curv = (const float*)d_in[7];
    float*       out  = (float*)d_out;

    const int E = in_sizes[0];
    const int N = in_sizes[2] / DIM;
    const int NB = (N + BW - 1) >> BW_SHIFT;           // 782 for N=100k
    const size_t bucketSlots = (size_t)NBMAX << CAP_SHIFT;

    char* ws = (char*)d_ws;
    auto align256 = [](size_t x) { return (x + 255) & ~(size_t)255; };
    size_t off = 0;
    int* cursorB            = (int*)(ws + off);            off += align256(NBMAX * 4);
    unsigned int* pairBuf   = (unsigned int*)(ws + off);   off += align256(bucketSlots * 4);
    unsigned short* Wbf1    = (unsigned short*)(ws + off); off += align256((size_t)DIM * DIM * 2);
    unsigned short* Wbf2    = (unsigned short*)(ws + off); off += align256((size_t)DIM * DIM * 2);
    unsigned short* zrowb   = (unsigned short*)(ws + off); off += align256(DIM * 2);
    unsigned short* h1b     = (unsigned short*)(ws + off); off += align256((size_t)N * DIM * 2);
    unsigned short* h2b     = (unsigned short*)(ws + off); off += align256((size_t)N * DIM * 2);

    const long long zoff_h1 = (long long)((char*)zrowb - (char*)h1b);
    const long long zoff_h2 = (long long)((char*)zrowb - (char*)h2b);

    const int numChunks    = (E + 4095) / 4096;
    const int numBatches16 = (N + 15) / 16;
    const int blocks16     = (numBatches16 + 3) / 4;

    // ---- prep (W->bf16, zrow, bucket cursors) ----
    prep_kernel<<<(DIM * DIM + 255) / 256, 256, 0, stream>>>(W1, W2, Wbf1, Wbf2,
                                                             zrowb, cursorB);
    // ---- merged: partition (blocks 0..numChunks) + layer-1 GEMM (rest) ----
    partition_and_gemm_kernel<<<numChunks + blocks16, 256, 0, stream>>>(
        src, dst, cursorB, pairBuf, emb, Wbf1, b1, curv, h1b, N, E, NB, numChunks);
    // ---- layer 2: edge-accumulate h1 -> mean -> GEMM2 -> h2 ----
    gather_acc_gemm<<<NB, 256, 0, stream>>>(h1b, pairBuf, cursorB, Wbf2, b2, h2b,
                                            zoff_h1, N);
    // ---- final: edge-accumulate h2 -> mean -> expmap0 -> out ----
    gather_acc_expmap<<<NB, 256, 0, stream>>>(h2b, pairBuf, cursorB, curv, out,
                                              zoff_h2, N);
}

// Round 12
// 193.161 us; speedup vs baseline: 6.0790x; 6.0790x over previous
//
#include <hip/hip_runtime.h>
#include <math.h>

#define DIM 64
#define EPSF 1e-15f

#define BW_SHIFT 8
#define BW (1 << BW_SHIFT)       // nodes per bucket (256)
#define CAP_SHIFT 12
#define CAP (1 << CAP_SHIFT)     // bucket capacity 4096 (mean 3061, ~19 sigma)
// NOTE: packing assumes src < 2^17 (N <= 131072) and NB <= 512.

typedef __attribute__((ext_vector_type(8))) short short8;
typedef __attribute__((ext_vector_type(4))) float floatx4;
typedef __attribute__((ext_vector_type(2))) float floatx2;
typedef __attribute__((ext_vector_type(4))) unsigned int uintx4;

// ---------------------------------------------------------------------------
__device__ __forceinline__ float group16_sum(float x) {
#pragma unroll
    for (int off = 1; off <= 8; off <<= 1)
        x += __shfl_xor(x, off, 64);
    return x;
}
__device__ __forceinline__ float group8_sum(float x) {
#pragma unroll
    for (int off = 1; off <= 4; off <<= 1)
        x += __shfl_xor(x, off, 64);
    return x;
}
__device__ __forceinline__ unsigned int f2bf(float x) {
    unsigned int u = __float_as_uint(x);
    u += 0x7fffu + ((u >> 16) & 1u);
    return u >> 16;
}
__device__ __forceinline__ float bflo(unsigned int u) { return __uint_as_float(u << 16); }
__device__ __forceinline__ float bfhi(unsigned int u) { return __uint_as_float(u & 0xFFFF0000u); }

// ---------------------------------------------------------------------------
// One-time prep: W->bf16, zero-row, bucket cursors to fixed bases b*CAP.
__global__ void prep_kernel(const float* __restrict__ W1, const float* __restrict__ W2,
                            unsigned short* __restrict__ Wbf1, unsigned short* __restrict__ Wbf2,
                            unsigned short* __restrict__ zrowb, int* __restrict__ cursorB, int NB) {
    int i = blockIdx.x * 256 + threadIdx.x;
    if (i < DIM * DIM) {
        Wbf1[i] = (unsigned short)f2bf(W1[i]);
        Wbf2[i] = (unsigned short)f2bf(W2[i]);
    }
    if (i < NB) cursorB[i] = i << CAP_SHIFT;
    if (blockIdx.x == 0 && threadIdx.x < 64) zrowb[threadIdx.x] = 0;
}

// ---------------------------------------------------------------------------
// Stage 1: partition edges into fixed-capacity bucket regions of pairBuf.
__global__ __launch_bounds__(256) void partition_kernel(
    const int* __restrict__ src, const int* __restrict__ dst,
    int* __restrict__ cursorB, unsigned int* __restrict__ pairBuf, int E, int NB)
{
    __shared__ int hist[512], gbase[512], lcur[512];
    int tid = threadIdx.x;
    for (int t = tid; t < NB; t += 256) { hist[t] = 0; lcur[t] = 0; }
    __syncthreads();
    int base = blockIdx.x * 4096;
    unsigned int packed[16]; int bkt[16];
#pragma unroll
    for (int i = 0; i < 16; ++i) {
        int e = base + i * 256 + tid;
        if (e < E) {
            int s = src[e], d = dst[e];
            bkt[i] = d >> BW_SHIFT;
            packed[i] = ((unsigned int)(d & (BW - 1)) << 17) | (unsigned int)s;
            atomicAdd(&hist[bkt[i]], 1);
        } else bkt[i] = -1;
    }
    __syncthreads();
    for (int t = tid; t < NB; t += 256)
        gbase[t] = hist[t] ? atomicAdd(&cursorB[t], hist[t]) : 0;
    __syncthreads();
#pragma unroll
    for (int i = 0; i < 16; ++i) {
        if (bkt[i] >= 0) {
            int rank = atomicAdd(&lcur[bkt[i]], 1);
            int p = gbase[bkt[i]] + rank;
            if (p < ((bkt[i] + 1) << CAP_SHIFT)) pairBuf[p] = packed[i];  // overflow guard
        }
    }
}

// ---------------------------------------------------------------------------
// Merged dispatch: blocks [0, NB) per-bucket counting sort; rest layer-1 GEMM.
union SharedU {
    struct {
        int edges[CAP];
        int stage[CAP];
        int hist[BW], cur[BW], tmp[BW];
    } s;                                  // 35 KB (sort path)
    unsigned int atile[4][16 * 36];       // 9.2 KB (gemm path)
};

__global__ __launch_bounds__(256, 4) void sort_and_gemm_kernel(
    const unsigned int* __restrict__ pairBuf, const int* __restrict__ cursorB,
    int* __restrict__ rowS, int* __restrict__ rowE, int* __restrict__ col,
    const float* __restrict__ in, const unsigned short* __restrict__ Wbf,
    const float* __restrict__ bias, const float* __restrict__ curv,
    unsigned short* __restrict__ outb, int N, int NB)
{
    __shared__ SharedU u;
    if ((int)blockIdx.x < NB) {
        const int b = blockIdx.x, t = threadIdx.x;
        const int base = b << CAP_SHIFT;
        int cnt = cursorB[b] - base;
        if (cnt > CAP) cnt = CAP;
        for (int i = t; i < cnt; i += 256) u.s.edges[i] = (int)pairBuf[base + i];
        u.s.hist[t] = 0;
        __syncthreads();
        for (int i = t; i < cnt; i += 256) atomicAdd(&u.s.hist[u.s.edges[i] >> 17], 1);
        __syncthreads();
        int hv = u.s.hist[t];
        u.s.tmp[t] = hv; __syncthreads();
        for (int off = 1; off < 256; off <<= 1) {
            int x = (t >= off) ? u.s.tmp[t - off] : 0; __syncthreads();
            u.s.tmp[t] += x; __syncthreads();
        }
        int excl = u.s.tmp[t] - hv;
        int node = (b << BW_SHIFT) + t;
        if (node < N) { rowS[node] = base + excl; rowE[node] = base + excl + hv; }
        u.s.cur[t] = excl;
        __syncthreads();
        for (int i = t; i < cnt; i += 256) {
            int v = u.s.edges[i];
            int pos = atomicAdd(&u.s.cur[v >> 17], 1);
            u.s.stage[pos] = v & 0x1FFFF;
        }
        __syncthreads();
        for (int i = t; i < cnt; i += 256) col[base + i] = u.s.stage[i];
    } else {
        const int bid = blockIdx.x - NB;
        const int gemmWaves = (gridDim.x - NB) << 2;
        const float sc = sqrtf(fabsf(curv[0]));
        const float CLIPF = 1.0f - 1e-7f;
        const int lane = threadIdx.x & 63;
        const int wid  = threadIdx.x >> 6;
        const int q = lane >> 4, r = lane & 15;
        const int numBatches = (N + 15) >> 4;
        const float4* in4 = (const float4*)in;

        short8 bfrag[4][2];
#pragma unroll
        for (int nt = 0; nt < 4; ++nt)
#pragma unroll
            for (int ks = 0; ks < 2; ++ks)
                bfrag[nt][ks] = *(const short8*)(Wbf + (nt * 16 + r) * 64 + ks * 32 + q * 8);

        float biasv[4];
#pragma unroll
        for (int nt = 0; nt < 4; ++nt) biasv[nt] = bias[nt * 16 + r];

        for (int batch = (bid << 2) + wid; batch < numBatches; batch += gemmWaves) {
            const int base = batch << 4;
#pragma unroll
            for (int it = 0; it < 4; ++it) {
                int m = it * 4 + q;
                int node = base + m;
                float4 v = make_float4(0.f, 0.f, 0.f, 0.f);
                if (node < N) v = in4[(size_t)node * 16 + r];
                float ss = group16_sum(v.x * v.x + v.y * v.y + v.z * v.z + v.w * v.w);
                float nrm = fmaxf(sqrtf(ss), EPSF);
                float a = fminf(sc * nrm, CLIPF);
                float g = atanhf(a) / (sc * nrm);
                unsigned int lo = f2bf(v.x * g) | (f2bf(v.y * g) << 16);
                unsigned int hi = f2bf(v.z * g) | (f2bf(v.w * g) << 16);
                *(uint2*)&u.atile[wid][m * 36 + r * 2] = make_uint2(lo, hi);
            }
            floatx4 accm[4];
#pragma unroll
            for (int nt = 0; nt < 4; ++nt) accm[nt] = (floatx4){0.f, 0.f, 0.f, 0.f};
#pragma unroll
            for (int ks = 0; ks < 2; ++ks) {
                uintx4 ua = *(const uintx4*)&u.atile[wid][r * 36 + q * 4 + ks * 16];
                short8 af = __builtin_bit_cast(short8, ua);
#pragma unroll
                for (int nt = 0; nt < 4; ++nt)
                    accm[nt] = __builtin_amdgcn_mfma_f32_16x16x32_bf16(af, bfrag[nt][ks], accm[nt], 0, 0, 0);
            }
#pragma unroll
            for (int nt = 0; nt < 4; ++nt)
#pragma unroll
                for (int reg = 0; reg < 4; ++reg) {
                    int node = base + q * 4 + reg;
                    if (node < N)
                        outb[(size_t)node * 64 + nt * 16 + r] =
                            (unsigned short)f2bf(accm[nt][reg] + biasv[nt]);
                }
        }
    }
}

// ---------------------------------------------------------------------------
// bf16 segmented gather, 16-deep MLP: 8-lane group g sums 128 B bf16 rows
// listed in col[start..end). Per iteration: 16 edges, each lane loads 2 col
// entries + 16 independent row chunks (16 KB/wave in flight), then packed adds.
__device__ __forceinline__ void gather_rows_bf16(
    const char* __restrict__ hb, const int* __restrict__ col,
    int start, int end, int dmax, long long zoff, int g, int r, int colMax,
    floatx2 acc2[4])
{
    const int roff = r << 4;
    for (int b = 0; (b << 4) < dmax; ++b) {
        int pos0 = start + (b << 4) + r;
        int pos1 = pos0 + 8;
        int cv0 = col[min(pos0, colMax)];
        int cv1 = col[min(pos1, colMax)];
        int sent0 = (pos0 < end) ? cv0 : -1;
        int sent1 = (pos1 < end) ? cv1 : -1;
        long long o[16];
#pragma unroll
        for (int i = 0; i < 8; ++i) {
            int s0 = __shfl(sent0, (g << 3) + i, 64);
            int s1 = __shfl(sent1, (g << 3) + i, 64);
            o[i]     = (s0 < 0) ? zoff : ((long long)s0 << 7);
            o[8 + i] = (s1 < 0) ? zoff : ((long long)s1 << 7);
        }
        uint4 uu[16];
#pragma unroll
        for (int i = 0; i < 16; ++i)
            uu[i] = *(const uint4*)(hb + o[i] + roff);
#pragma unroll
        for (int i = 0; i < 16; ++i) {
            acc2[0] += (floatx2){bflo(uu[i].x), bfhi(uu[i].x)};
            acc2[1] += (floatx2){bflo(uu[i].y), bfhi(uu[i].y)};
            acc2[2] += (floatx2){bflo(uu[i].z), bfhi(uu[i].z)};
            acc2[3] += (floatx2){bflo(uu[i].w), bfhi(uu[i].w)};
        }
    }
}

// ---------------------------------------------------------------------------
// Layer 2 fused: u = mean gather_bf16(h1); h2 = u @ W^T + b -> bf16.
__global__ __launch_bounds__(256, 4) void gather_gemm_mfma(
    const unsigned short* __restrict__ h, const int* __restrict__ rowS,
    const int* __restrict__ rowE, const int* __restrict__ col,
    const unsigned short* __restrict__ Wbf, const float* __restrict__ bias,
    unsigned short* __restrict__ outb, long long zoff, int N, int colMax)
{
    __shared__ unsigned int AtileU[4][16 * 36];
    const int lane = threadIdx.x & 63;
    const int wid  = threadIdx.x >> 6;
    const int q = lane >> 4, r = lane & 15;
    const int g8 = lane >> 3, r8 = lane & 7;
    const int wavesTotal = (gridDim.x * blockDim.x) >> 6;
    const int numBatches = (N + 15) >> 4;
    const char* hb = (const char*)h;

    short8 bfrag[4][2];
#pragma unroll
    for (int nt = 0; nt < 4; ++nt)
#pragma unroll
        for (int ks = 0; ks < 2; ++ks)
            bfrag[nt][ks] = *(const short8*)(Wbf + (nt * 16 + r) * 64 + ks * 32 + q * 8);

    float biasv[4];
#pragma unroll
    for (int nt = 0; nt < 4; ++nt) biasv[nt] = bias[nt * 16 + r];

    for (int batch = (blockIdx.x << 2) + wid; batch < numBatches; batch += wavesTotal) {
        const int base = batch << 4;
#pragma unroll
        for (int it = 0; it < 2; ++it) {
            int m = it * 8 + g8;
            int node = base + m;
            int start = 0, end = 0;
            if (node < N) { start = rowS[node]; end = rowE[node]; }
            int deg = end - start;
            int dmax = max(deg, __shfl_xor(deg, 8, 64));
            dmax = max(dmax, __shfl_xor(dmax, 16, 64));
            dmax = max(dmax, __shfl_xor(dmax, 32, 64));
            floatx2 acc2[4] = {{0.f,0.f},{0.f,0.f},{0.f,0.f},{0.f,0.f}};
            gather_rows_bf16(hb, col, start, end, dmax, zoff, g8, r8, colMax, acc2);
            float inv = (deg > 0) ? 1.f / (float)deg : 0.f;
            unsigned int u0 = f2bf(acc2[0].x * inv) | (f2bf(acc2[0].y * inv) << 16);
            unsigned int u1 = f2bf(acc2[1].x * inv) | (f2bf(acc2[1].y * inv) << 16);
            unsigned int u2 = f2bf(acc2[2].x * inv) | (f2bf(acc2[2].y * inv) << 16);
            unsigned int u3 = f2bf(acc2[3].x * inv) | (f2bf(acc2[3].y * inv) << 16);
            *(uint4*)&AtileU[wid][m * 36 + r8 * 4] = make_uint4(u0, u1, u2, u3);
        }
        floatx4 accm[4];
#pragma unroll
        for (int nt = 0; nt < 4; ++nt) accm[nt] = (floatx4){0.f, 0.f, 0.f, 0.f};
#pragma unroll
        for (int ks = 0; ks < 2; ++ks) {
            uintx4 ua = *(const uintx4*)&AtileU[wid][r * 36 + q * 4 + ks * 16];
            short8 af = __builtin_bit_cast(short8, ua);
#pragma unroll
            for (int nt = 0; nt < 4; ++nt)
                accm[nt] = __builtin_amdgcn_mfma_f32_16x16x32_bf16(af, bfrag[nt][ks], accm[nt], 0, 0, 0);
        }
#pragma unroll
        for (int nt = 0; nt < 4; ++nt)
#pragma unroll
            for (int reg = 0; reg < 4; ++reg) {
                int node = base + q * 4 + reg;
                if (node < N)
                    outb[(size_t)node * 64 + nt * 16 + r] =
                        (unsigned short)f2bf(accm[nt][reg] + biasv[nt]);
            }
    }
}

// ---------------------------------------------------------------------------
// Final: out = expmap0(mean gather_bf16(h2)) -> fp32. 8 nodes per wave.
__global__ __launch_bounds__(256, 4) void gather_expmap8(
    const unsigned short* __restrict__ h, const int* __restrict__ rowS,
    const int* __restrict__ rowE, const int* __restrict__ col,
    const float* __restrict__ curv, float* __restrict__ out,
    long long zoff, int N, int colMax)
{
    const float sc = sqrtf(fabsf(curv[0]));
    const int lane = threadIdx.x & 63;
    const int wid  = threadIdx.x >> 6;
    const int g8 = lane >> 3, r8 = lane & 7;
    const int wavesTotal = (gridDim.x * blockDim.x) >> 6;
    const int numBatches = (N + 7) >> 3;
    const char* hb = (const char*)h;
    float4* out4 = (float4*)out;

    for (int batch = (blockIdx.x << 2) + wid; batch < numBatches; batch += wavesTotal) {
        int node = (batch << 3) + g8;
        int start = 0, end = 0;
        if (node < N) { start = rowS[node]; end = rowE[node]; }
        int deg = end - start;
        int dmax = max(deg, __shfl_xor(deg, 8, 64));
        dmax = max(dmax, __shfl_xor(dmax, 16, 64));
        dmax = max(dmax, __shfl_xor(dmax, 32, 64));
        floatx2 acc2[4] = {{0.f,0.f},{0.f,0.f},{0.f,0.f},{0.f,0.f}};
        gather_rows_bf16(hb, col, start, end, dmax, zoff, g8, r8, colMax, acc2);
        float inv = (deg > 0) ? 1.f / (float)deg : 0.f;
        float v[8], ss = 0.f;
#pragma unroll
        for (int j = 0; j < 4; ++j) {
            v[2*j]   = acc2[j].x * inv;
            v[2*j+1] = acc2[j].y * inv;
            ss += v[2*j] * v[2*j] + v[2*j+1] * v[2*j+1];
        }
        ss = group8_sum(ss);
        float nrm = fmaxf(sqrtf(ss), EPSF);
        float a = sc * nrm;
        float f = tanhf(a) / a;
        if (node < N) {
            out4[(size_t)node * 16 + r8 * 2]     = make_float4(v[0] * f, v[1] * f, v[2] * f, v[3] * f);
            out4[(size_t)node * 16 + r8 * 2 + 1] = make_float4(v[4] * f, v[5] * f, v[6] * f, v[7] * f);
        }
    }
}

// ---------------------------------------------------------------------------
extern "C" void kernel_launch(void* const* d_in, const int* in_sizes, int n_in,
                              void* d_out, int out_size, void* d_ws, size_t ws_size,
                              hipStream_t stream)
{
    const int*   src  = (const int*)d_in[0];
    const int*   dst  = (const int*)d_in[1];
    const float* emb  = (const float*)d_in[2];
    const float* W1   = (const float*)d_in[3];
    const float* b1   = (const float*)d_in[4];
    const float* W2   = (const float*)d_in[5];
    const float* b2   = (const float*)d_in[6];
    const float* curv = (const float*)d_in[7];
    float*       out  = (float*)d_out;

    const int E = in_sizes[0];
    const int N = in_sizes[2] / DIM;
    const int NB = (N + BW - 1) >> BW_SHIFT;
    const size_t bucketSlots = (size_t)NB << CAP_SHIFT;
    const int colMax = (int)bucketSlots - 1;

    char* ws = (char*)d_ws;
    auto align256 = [](size_t x) { return (x + 255) & ~(size_t)255; };
    size_t off = 0;
    int* cursorB            = (int*)(ws + off);            off += align256(512 * 4);
    int* rowS               = (int*)(ws + off);            off += align256((size_t)N * 4);
    int* rowE               = (int*)(ws + off);            off += align256((size_t)N * 4);
    unsigned int* pairBuf   = (unsigned int*)(ws + off);   off += align256(bucketSlots * 4);
    int* col                = (int*)(ws + off);            off += align256(bucketSlots * 4);
    unsigned short* Wbf1    = (unsigned short*)(ws + off); off += align256((size_t)DIM * DIM * 2);
    unsigned short* Wbf2    = (unsigned short*)(ws + off); off += align256((size_t)DIM * DIM * 2);
    unsigned short* zrowb   = (unsigned short*)(ws + off); off += align256(DIM * 2);
    unsigned short* h1b     = (unsigned short*)(ws + off); off += align256((size_t)N * DIM * 2);
    unsigned short* h2b     = (unsigned short*)(ws + off); off += align256((size_t)N * DIM * 2);

    const long long zoff_h1 = (long long)((char*)zrowb - (char*)h1b);
    const long long zoff_h2 = (long long)((char*)zrowb - (char*)h2b);

    const int chunkBlocks  = (E + 4095) / 4096;
    const int numBatches16 = (N + 15) / 16;
    const int blocks16     = (numBatches16 + 3) / 4;
    const int numBatches8  = (N + 7) / 8;
    const int blocks8      = (numBatches8 + 3) / 4;

    // ---- prep (W->bf16, zrow, bucket cursors) ----
    prep_kernel<<<(DIM * DIM + 255) / 256, 256, 0, stream>>>(W1, W2, Wbf1, Wbf2,
                                                             zrowb, cursorB, NB);
    // ---- CSR partition into fixed buckets ----
    partition_kernel<<<chunkBlocks, 256, 0, stream>>>(src, dst, cursorB, pairBuf, E, NB);
    // ---- merged: per-bucket sort (blocks 0..NB) + layer-1 GEMM (rest) ----
    sort_and_gemm_kernel<<<NB + blocks16, 256, 0, stream>>>(
        pairBuf, cursorB, rowS, rowE, col, emb, Wbf1, b1, curv, h1b, N, NB);
    // ---- layer 2: h2(bf16) = (mean gather h1) @ W2^T + b2 ----
    gather_gemm_mfma<<<blocks16, 256, 0, stream>>>(h1b, rowS, rowE, col, Wbf2, b2, h2b,
                                                   zoff_h1, N, colMax);
    // ---- final: out(fp32) = expmap0(mean gather h2) ----
    gather_expmap8<<<blocks8, 256, 0, stream>>>(h2b, rowS, rowE, col, curv, out,
                                                zoff_h2, N, colMax);
}

// Round 13
// 192.201 us; speedup vs baseline: 6.1094x; 1.0050x over previous
//
#include <hip/hip_runtime.h>
#include <math.h>

#define DIM 64
#define EPSF 1e-15f

#define BW_SHIFT 8
#define BW (1 << BW_SHIFT)       // nodes per bucket (256)
#define CAP_SHIFT 12
#define CAP (1 << CAP_SHIFT)     // bucket capacity 4096 (mean 3061, ~19 sigma)
// NOTE: packing assumes src < 2^17 (N <= 131072) and NB <= 512.

typedef __attribute__((ext_vector_type(8))) short short8;
typedef __attribute__((ext_vector_type(4))) float floatx4;
typedef __attribute__((ext_vector_type(2))) float floatx2;
typedef __attribute__((ext_vector_type(4))) unsigned int uintx4;

// ---------------------------------------------------------------------------
__device__ __forceinline__ float group16_sum(float x) {
#pragma unroll
    for (int off = 1; off <= 8; off <<= 1)
        x += __shfl_xor(x, off, 64);
    return x;
}
__device__ __forceinline__ float group8_sum(float x) {
#pragma unroll
    for (int off = 1; off <= 4; off <<= 1)
        x += __shfl_xor(x, off, 64);
    return x;
}
__device__ __forceinline__ unsigned int f2bf(float x) {
    unsigned int u = __float_as_uint(x);
    u += 0x7fffu + ((u >> 16) & 1u);
    return u >> 16;
}
__device__ __forceinline__ float bflo(unsigned int u) { return __uint_as_float(u << 16); }
__device__ __forceinline__ float bfhi(unsigned int u) { return __uint_as_float(u & 0xFFFF0000u); }

// ---------------------------------------------------------------------------
// Stage 1 (merged): blocks [0, numChunks) partition edges into fixed-capacity
// bucket regions of pairBuf (cursor counts from 0, slot = (bkt<<CAP)+cursor);
// block numChunks converts W1/W2 -> bf16 and zeroes zrow (prep folded in).
__global__ __launch_bounds__(256) void partition_prep_kernel(
    const int* __restrict__ src, const int* __restrict__ dst,
    int* __restrict__ cursorB, unsigned int* __restrict__ pairBuf,
    const float* __restrict__ W1, const float* __restrict__ W2,
    unsigned short* __restrict__ Wbf1, unsigned short* __restrict__ Wbf2,
    unsigned short* __restrict__ zrowb, int E, int NB, int numChunks)
{
    if ((int)blockIdx.x >= numChunks) {
        // ---- prep block ----
        for (int i = threadIdx.x; i < DIM * DIM; i += 256) {
            Wbf1[i] = (unsigned short)f2bf(W1[i]);
            Wbf2[i] = (unsigned short)f2bf(W2[i]);
        }
        if (threadIdx.x < DIM) zrowb[threadIdx.x] = 0;
        return;
    }
    __shared__ int hist[512], gbase[512], lcur[512];
    int tid = threadIdx.x;
    for (int t = tid; t < NB; t += 256) { hist[t] = 0; lcur[t] = 0; }
    __syncthreads();
    int base = blockIdx.x * 4096;
    unsigned int packed[16]; int bkt[16];
#pragma unroll
    for (int i = 0; i < 16; ++i) {
        int e = base + i * 256 + tid;
        if (e < E) {
            int s = src[e], d = dst[e];
            bkt[i] = d >> BW_SHIFT;
            packed[i] = ((unsigned int)(d & (BW - 1)) << 17) | (unsigned int)s;
            atomicAdd(&hist[bkt[i]], 1);
        } else bkt[i] = -1;
    }
    __syncthreads();
    for (int t = tid; t < NB; t += 256)
        gbase[t] = hist[t] ? atomicAdd(&cursorB[t], hist[t]) : 0;
    __syncthreads();
#pragma unroll
    for (int i = 0; i < 16; ++i) {
        if (bkt[i] >= 0) {
            int rank = gbase[bkt[i]] + atomicAdd(&lcur[bkt[i]], 1);
            if (rank < CAP)                                   // overflow guard
                pairBuf[((size_t)bkt[i] << CAP_SHIFT) + rank] = packed[i];
        }
    }
}

// ---------------------------------------------------------------------------
// Merged dispatch: blocks [0, NB) per-bucket counting sort; rest layer-1 GEMM.
union SharedU {
    struct {
        int edges[CAP];
        int stage[CAP];
        int hist[BW], cur[BW], tmp[BW];
    } s;                                  // 35 KB (sort path)
    unsigned int atile[4][16 * 36];       // 9.2 KB (gemm path)
};

__global__ __launch_bounds__(256, 4) void sort_and_gemm_kernel(
    const unsigned int* __restrict__ pairBuf, const int* __restrict__ cursorB,
    int* __restrict__ rowS, int* __restrict__ rowE, int* __restrict__ col,
    const float* __restrict__ in, const unsigned short* __restrict__ Wbf,
    const float* __restrict__ bias, const float* __restrict__ curv,
    unsigned short* __restrict__ outb, int N, int NB)
{
    __shared__ SharedU u;
    if ((int)blockIdx.x < NB) {
        const int b = blockIdx.x, t = threadIdx.x;
        const int base = b << CAP_SHIFT;
        int cnt = cursorB[b];
        if (cnt > CAP) cnt = CAP;
        for (int i = t; i < cnt; i += 256) u.s.edges[i] = (int)pairBuf[base + i];
        u.s.hist[t] = 0;
        __syncthreads();
        for (int i = t; i < cnt; i += 256) atomicAdd(&u.s.hist[u.s.edges[i] >> 17], 1);
        __syncthreads();
        int hv = u.s.hist[t];
        u.s.tmp[t] = hv; __syncthreads();
        for (int off = 1; off < 256; off <<= 1) {
            int x = (t >= off) ? u.s.tmp[t - off] : 0; __syncthreads();
            u.s.tmp[t] += x; __syncthreads();
        }
        int excl = u.s.tmp[t] - hv;
        int node = (b << BW_SHIFT) + t;
        if (node < N) { rowS[node] = base + excl; rowE[node] = base + excl + hv; }
        u.s.cur[t] = excl;
        __syncthreads();
        for (int i = t; i < cnt; i += 256) {
            int v = u.s.edges[i];
            int pos = atomicAdd(&u.s.cur[v >> 17], 1);
            u.s.stage[pos] = v & 0x1FFFF;
        }
        __syncthreads();
        for (int i = t; i < cnt; i += 256) col[base + i] = u.s.stage[i];
    } else {
        const int bid = blockIdx.x - NB;
        const int gemmWaves = (gridDim.x - NB) << 2;
        const float sc = sqrtf(fabsf(curv[0]));
        const float CLIPF = 1.0f - 1e-7f;
        const int lane = threadIdx.x & 63;
        const int wid  = threadIdx.x >> 6;
        const int q = lane >> 4, r = lane & 15;
        const int numBatches = (N + 15) >> 4;
        const float4* in4 = (const float4*)in;

        short8 bfrag[4][2];
#pragma unroll
        for (int nt = 0; nt < 4; ++nt)
#pragma unroll
            for (int ks = 0; ks < 2; ++ks)
                bfrag[nt][ks] = *(const short8*)(Wbf + (nt * 16 + r) * 64 + ks * 32 + q * 8);

        float biasv[4];
#pragma unroll
        for (int nt = 0; nt < 4; ++nt) biasv[nt] = bias[nt * 16 + r];

        for (int batch = (bid << 2) + wid; batch < numBatches; batch += gemmWaves) {
            const int base = batch << 4;
#pragma unroll
            for (int it = 0; it < 4; ++it) {
                int m = it * 4 + q;
                int node = base + m;
                float4 v = make_float4(0.f, 0.f, 0.f, 0.f);
                if (node < N) v = in4[(size_t)node * 16 + r];
                float ss = group16_sum(v.x * v.x + v.y * v.y + v.z * v.z + v.w * v.w);
                float nrm = fmaxf(sqrtf(ss), EPSF);
                float a = fminf(sc * nrm, CLIPF);
                float g = atanhf(a) / (sc * nrm);
                unsigned int lo = f2bf(v.x * g) | (f2bf(v.y * g) << 16);
                unsigned int hi = f2bf(v.z * g) | (f2bf(v.w * g) << 16);
                *(uint2*)&u.atile[wid][m * 36 + r * 2] = make_uint2(lo, hi);
            }
            floatx4 accm[4];
#pragma unroll
            for (int nt = 0; nt < 4; ++nt) accm[nt] = (floatx4){0.f, 0.f, 0.f, 0.f};
#pragma unroll
            for (int ks = 0; ks < 2; ++ks) {
                uintx4 ua = *(const uintx4*)&u.atile[wid][r * 36 + q * 4 + ks * 16];
                short8 af = __builtin_bit_cast(short8, ua);
#pragma unroll
                for (int nt = 0; nt < 4; ++nt)
                    accm[nt] = __builtin_amdgcn_mfma_f32_16x16x32_bf16(af, bfrag[nt][ks], accm[nt], 0, 0, 0);
            }
#pragma unroll
            for (int nt = 0; nt < 4; ++nt)
#pragma unroll
                for (int reg = 0; reg < 4; ++reg) {
                    int node = base + q * 4 + reg;
                    if (node < N)
                        outb[(size_t)node * 64 + nt * 16 + r] =
                            (unsigned short)f2bf(accm[nt][reg] + biasv[nt]);
                }
        }
    }
}

// ---------------------------------------------------------------------------
// bf16 segmented gather, 8-deep MLP (R8 best): 8-lane group g sums 128 B rows
// listed in col[start..end); 8 independent row loads in flight per block.
__device__ __forceinline__ void gather_rows_bf16(
    const char* __restrict__ hb, const int* __restrict__ col,
    int start, int end, int dmax, long long zoff, int g, int r, int colMax,
    floatx2 acc2[4])
{
    const int roff = r << 4;
    for (int b = 0; (b << 3) < dmax; ++b) {
        int pos = start + (b << 3) + r;
        int cv = col[min(pos, colMax)];
        int sent = (pos < end) ? cv : -1;
        int lim = dmax - (b << 3); if (lim > 8) lim = 8;
        if (lim == 8) {
            long long o[8];
#pragma unroll
            for (int i = 0; i < 8; ++i) {
                int s = __shfl(sent, (g << 3) + i, 64);
                o[i] = (s < 0) ? zoff : ((long long)s << 7);
            }
#pragma unroll
            for (int i = 0; i < 8; ++i) {
                uint4 uu = *(const uint4*)(hb + o[i] + roff);
                acc2[0] += (floatx2){bflo(uu.x), bfhi(uu.x)};
                acc2[1] += (floatx2){bflo(uu.y), bfhi(uu.y)};
                acc2[2] += (floatx2){bflo(uu.z), bfhi(uu.z)};
                acc2[3] += (floatx2){bflo(uu.w), bfhi(uu.w)};
            }
        } else {
            for (int i = 0; i < lim; ++i) {
                int s = __shfl(sent, (g << 3) + i, 64);
                long long o = (s < 0) ? zoff : ((long long)s << 7);
                uint4 uu = *(const uint4*)(hb + o + roff);
                acc2[0] += (floatx2){bflo(uu.x), bfhi(uu.x)};
                acc2[1] += (floatx2){bflo(uu.y), bfhi(uu.y)};
                acc2[2] += (floatx2){bflo(uu.z), bfhi(uu.z)};
                acc2[3] += (floatx2){bflo(uu.w), bfhi(uu.w)};
            }
        }
    }
}

// ---------------------------------------------------------------------------
// Layer 2 fused: u = mean gather_bf16(h1); h2 = u @ W^T + b -> bf16.
__global__ __launch_bounds__(256, 4) void gather_gemm_mfma(
    const unsigned short* __restrict__ h, const int* __restrict__ rowS,
    const int* __restrict__ rowE, const int* __restrict__ col,
    const unsigned short* __restrict__ Wbf, const float* __restrict__ bias,
    unsigned short* __restrict__ outb, long long zoff, int N, int colMax)
{
    __shared__ unsigned int AtileU[4][16 * 36];
    const int lane = threadIdx.x & 63;
    const int wid  = threadIdx.x >> 6;
    const int q = lane >> 4, r = lane & 15;
    const int g8 = lane >> 3, r8 = lane & 7;
    const int wavesTotal = (gridDim.x * blockDim.x) >> 6;
    const int numBatches = (N + 15) >> 4;
    const char* hb = (const char*)h;

    short8 bfrag[4][2];
#pragma unroll
    for (int nt = 0; nt < 4; ++nt)
#pragma unroll
        for (int ks = 0; ks < 2; ++ks)
            bfrag[nt][ks] = *(const short8*)(Wbf + (nt * 16 + r) * 64 + ks * 32 + q * 8);

    float biasv[4];
#pragma unroll
    for (int nt = 0; nt < 4; ++nt) biasv[nt] = bias[nt * 16 + r];

    for (int batch = (blockIdx.x << 2) + wid; batch < numBatches; batch += wavesTotal) {
        const int base = batch << 4;
#pragma unroll
        for (int it = 0; it < 2; ++it) {
            int m = it * 8 + g8;
            int node = base + m;
            int start = 0, end = 0;
            if (node < N) { start = rowS[node]; end = rowE[node]; }
            int deg = end - start;
            int dmax = max(deg, __shfl_xor(deg, 8, 64));
            dmax = max(dmax, __shfl_xor(dmax, 16, 64));
            dmax = max(dmax, __shfl_xor(dmax, 32, 64));
            floatx2 acc2[4] = {{0.f,0.f},{0.f,0.f},{0.f,0.f},{0.f,0.f}};
            gather_rows_bf16(hb, col, start, end, dmax, zoff, g8, r8, colMax, acc2);
            float inv = (deg > 0) ? 1.f / (float)deg : 0.f;
            unsigned int u0 = f2bf(acc2[0].x * inv) | (f2bf(acc2[0].y * inv) << 16);
            unsigned int u1 = f2bf(acc2[1].x * inv) | (f2bf(acc2[1].y * inv) << 16);
            unsigned int u2 = f2bf(acc2[2].x * inv) | (f2bf(acc2[2].y * inv) << 16);
            unsigned int u3 = f2bf(acc2[3].x * inv) | (f2bf(acc2[3].y * inv) << 16);
            *(uint4*)&AtileU[wid][m * 36 + r8 * 4] = make_uint4(u0, u1, u2, u3);
        }
        floatx4 accm[4];
#pragma unroll
        for (int nt = 0; nt < 4; ++nt) accm[nt] = (floatx4){0.f, 0.f, 0.f, 0.f};
#pragma unroll
        for (int ks = 0; ks < 2; ++ks) {
            uintx4 ua = *(const uintx4*)&AtileU[wid][r * 36 + q * 4 + ks * 16];
            short8 af = __builtin_bit_cast(short8, ua);
#pragma unroll
            for (int nt = 0; nt < 4; ++nt)
                accm[nt] = __builtin_amdgcn_mfma_f32_16x16x32_bf16(af, bfrag[nt][ks], accm[nt], 0, 0, 0);
        }
#pragma unroll
        for (int nt = 0; nt < 4; ++nt)
#pragma unroll
            for (int reg = 0; reg < 4; ++reg) {
                int node = base + q * 4 + reg;
                if (node < N)
                    outb[(size_t)node * 64 + nt * 16 + r] =
                        (unsigned short)f2bf(accm[nt][reg] + biasv[nt]);
            }
    }
}

// ---------------------------------------------------------------------------
// Final: out = expmap0(mean gather_bf16(h2)) -> fp32. 8 nodes per wave.
__global__ __launch_bounds__(256, 6) void gather_expmap8(
    const unsigned short* __restrict__ h, const int* __restrict__ rowS,
    const int* __restrict__ rowE, const int* __restrict__ col,
    const float* __restrict__ curv, float* __restrict__ out,
    long long zoff, int N, int colMax)
{
    const float sc = sqrtf(fabsf(curv[0]));
    const int lane = threadIdx.x & 63;
    const int wid  = threadIdx.x >> 6;
    const int g8 = lane >> 3, r8 = lane & 7;
    const int wavesTotal = (gridDim.x * blockDim.x) >> 6;
    const int numBatches = (N + 7) >> 3;
    const char* hb = (const char*)h;
    float4* out4 = (float4*)out;

    for (int batch = (blockIdx.x << 2) + wid; batch < numBatches; batch += wavesTotal) {
        int node = (batch << 3) + g8;
        int start = 0, end = 0;
        if (node < N) { start = rowS[node]; end = rowE[node]; }
        int deg = end - start;
        int dmax = max(deg, __shfl_xor(deg, 8, 64));
        dmax = max(dmax, __shfl_xor(dmax, 16, 64));
        dmax = max(dmax, __shfl_xor(dmax, 32, 64));
        floatx2 acc2[4] = {{0.f,0.f},{0.f,0.f},{0.f,0.f},{0.f,0.f}};
        gather_rows_bf16(hb, col, start, end, dmax, zoff, g8, r8, colMax, acc2);
        float inv = (deg > 0) ? 1.f / (float)deg : 0.f;
        float v[8], ss = 0.f;
#pragma unroll
        for (int j = 0; j < 4; ++j) {
            v[2*j]   = acc2[j].x * inv;
            v[2*j+1] = acc2[j].y * inv;
            ss += v[2*j] * v[2*j] + v[2*j+1] * v[2*j+1];
        }
        ss = group8_sum(ss);
        float nrm = fmaxf(sqrtf(ss), EPSF);
        float a = sc * nrm;
        float f = tanhf(a) / a;
        if (node < N) {
            out4[(size_t)node * 16 + r8 * 2]     = make_float4(v[0] * f, v[1] * f, v[2] * f, v[3] * f);
            out4[(size_t)node * 16 + r8 * 2 + 1] = make_float4(v[4] * f, v[5] * f, v[6] * f, v[7] * f);
        }
    }
}

// ---------------------------------------------------------------------------
extern "C" void kernel_launch(void* const* d_in, const int* in_sizes, int n_in,
                              void* d_out, int out_size, void* d_ws, size_t ws_size,
                              hipStream_t stream)
{
    const int*   src  = (const int*)d_in[0];
    const int*   dst  = (const int*)d_in[1];
    const float* emb  = (const float*)d_in[2];
    const float* W1   = (const float*)d_in[3];
    const float* b1   = (const float*)d_in[4];
    const float* W2   = (const float*)d_in[5];
    const float* b2   = (const float*)d_in[6];
    const float* curv = (const float*)d_in[7];
    float*       out  = (float*)d_out;

    const int E = in_sizes[0];
    const int N = in_sizes[2] / DIM;
    const int NB = (N + BW - 1) >> BW_SHIFT;
    const size_t bucketSlots = (size_t)NB << CAP_SHIFT;
    const int colMax = (int)bucketSlots - 1;

    char* ws = (char*)d_ws;
    auto align256 = [](size_t x) { return (x + 255) & ~(size_t)255; };
    size_t off = 0;
    int* cursorB            = (int*)(ws + off);            off += align256(512 * 4);
    int* rowS               = (int*)(ws + off);            off += align256((size_t)N * 4);
    int* rowE               = (int*)(ws + off);            off += align256((size_t)N * 4);
    unsigned int* pairBuf   = (unsigned int*)(ws + off);   off += align256(bucketSlots * 4);
    int* col                = (int*)(ws + off);            off += align256(bucketSlots * 4);
    unsigned short* Wbf1    = (unsigned short*)(ws + off); off += align256((size_t)DIM * DIM * 2);
    unsigned short* Wbf2    = (unsigned short*)(ws + off); off += align256((size_t)DIM * DIM * 2);
    unsigned short* zrowb   = (unsigned short*)(ws + off); off += align256(DIM * 2);
    unsigned short* h1b     = (unsigned short*)(ws + off); off += align256((size_t)N * DIM * 2);
    unsigned short* h2b     = (unsigned short*)(ws + off); off += align256((size_t)N * DIM * 2);

    const long long zoff_h1 = (long long)((char*)zrowb - (char*)h1b);
    const long long zoff_h2 = (long long)((char*)zrowb - (char*)h2b);

    const int chunkBlocks  = (E + 4095) / 4096;
    const int numBatches16 = (N + 15) / 16;
    const int blocks16     = (numBatches16 + 3) / 4;
    const int numBatches8  = (N + 7) / 8;
    const int blocks8      = (numBatches8 + 3) / 4;

    // ---- cursor zero (cursor counts from 0 now) ----
    hipMemsetAsync(cursorB, 0, 512 * 4, stream);
    // ---- merged: partition (blocks 0..chunkBlocks) + prep (last block) ----
    partition_prep_kernel<<<chunkBlocks + 1, 256, 0, stream>>>(
        src, dst, cursorB, pairBuf, W1, W2, Wbf1, Wbf2, zrowb, E, NB, chunkBlocks);
    // ---- merged: per-bucket sort (blocks 0..NB) + layer-1 GEMM (rest) ----
    sort_and_gemm_kernel<<<NB + blocks16, 256, 0, stream>>>(
        pairBuf, cursorB, rowS, rowE, col, emb, Wbf1, b1, curv, h1b, N, NB);
    // ---- layer 2: h2(bf16) = (mean gather h1) @ W2^T + b2 ----
    gather_gemm_mfma<<<blocks16, 256, 0, stream>>>(h1b, rowS, rowE, col, Wbf2, b2, h2b,
                                                   zoff_h1, N, colMax);
    // ---- final: out(fp32) = expmap0(mean gather h2) ----
    gather_expmap8<<<blocks8, 256, 0, stream>>>(h2b, rowS, rowE, col, curv, out,
                                                zoff_h2, N, colMax);
}